// Round 4
// baseline (99.070 us; speedup 1.0000x reference)
//
#include <hip/hip_runtime.h>
#include <hip/hip_fp16.h>

#define BATCH 16
#define C_IN  64
#define HH    64
#define WW    64
#define COUT  64
#define KK    9
#define HW    4096
#define CK    576
#define WROWS 15    // staged window rows: [R4-5, R4+9] for rows R4..R4+3
#define WLO   5

typedef _Float16 f16x8 __attribute__((ext_vector_type(8)));
typedef float    f32x4 __attribute__((ext_vector_type(4)));

__device__ __forceinline__ unsigned short f32_to_f16u(float f) {
    _Float16 h = (_Float16)f;       // v_cvt_f16_f32, RNE
    unsigned short u;
    __builtin_memcpy(&u, &h, 2);
    return u;
}

__device__ __forceinline__ __half2 as_h2(unsigned int u) {
    __half2 r; __builtin_memcpy(&r, &u, 4); return r;
}
__device__ __forceinline__ unsigned int as_u32(__half2 v) {
    unsigned int u; __builtin_memcpy(&u, &v, 4); return u;
}

// Fused prep, R11: x-transpose WITHOUT LDS (R10 post-mortem: tile transpose
// had ~8-way write bank conflicts + scalar b16 writes).  Thread t = (px=t&63,
// 16 channels cg*16..): dword loads coalesced over px (64 lanes x consecutive
// px = 256 B/instr), cvt+pack in regs, two contiguous uint4 stores per lane.
// Blocks 1024..1167: w -> wt in MFMA A-fragment order (unchanged).
__global__ __launch_bounds__(256) void prep_kernel(
    const float* __restrict__ x, const float* __restrict__ w,
    unsigned short* __restrict__ xt, unsigned short* __restrict__ wt) {
    const int t = threadIdx.x;
    const int blk = blockIdx.x;
    if (blk < 1024) {
        const int b = blk >> 6, y = blk & 63;
        const int px = t & 63, cg = t >> 6;
        const float* xp = x + ((b * 64 + cg * 16) * 64 + y) * 64 + px;
        unsigned int u[8];
#pragma unroll
        for (int j = 0; j < 8; ++j) {
            const float v0 = xp[(2 * j) * HW];
            const float v1 = xp[(2 * j + 1) * HW];
            u[j] = (unsigned)f32_to_f16u(v0) | ((unsigned)f32_to_f16u(v1) << 16);
        }
        unsigned short* dst = xt + ((b * HW) + y * 64 + px) * 64 + cg * 16;
        *(uint4*)dst = *(const uint4*)&u[0];
        *(uint4*)(dst + 8) = *(const uint4*)&u[4];
    } else {
        const int i = (blk - 1024) * 256 + t;  // 0..36863
        const int j = i & 7;
        const int l = (i >> 3) & 63;
        const int ot = (i >> 9) & 3;
        const int r = i >> 11;           // 0..17
        const int ks = r % 6, kc = r / 6;
        const int o  = ot * 16 + (l & 15);
        const int kk = ks * 32 + (l >> 4) * 8 + j;
        const int tap = kk >> 6, c = kk & 63;
        const int k = kc * 3 + tap;
        wt[i] = f32_to_f16u(w[o * CK + c * KK + k]);
    }
}

// Main, R11.  Grid 256 = one block per CU, ONE round.  Block = 512 thr =
// 8 waves owns FOUR rows (two row-pairs) of one batch, sharing a single
// 15-row swizzled window [4R-5, 4R+9] (122.9 KB).  vs R10: staging traffic
// halved, pair-1 has zero staging wait, inter-round CU serialization gone.
// Params for both pairs are loaded in the prologue (regs) so only pair-1's
// param-VALU phase (~0.5 us) sits between the two gather+MFMA phases.
// Inner loop unchanged from R10 (in-register bfrag, XOR-swizzled window,
// exact global-fallback escape path).
__global__ __launch_bounds__(512, 1) void dcn_main_kernel(
    const float* __restrict__ offset, const float* __restrict__ mask,
    const unsigned short* __restrict__ xt, const unsigned short* __restrict__ wt,
    const float* __restrict__ bias, float* __restrict__ out) {
    __shared__ __align__(16) unsigned short win[WROWS * 4096];   // 122880 B
    __shared__ __align__(16) int PWw[2][576 * 4];                //  18432 B
    __shared__ __align__(16) unsigned int PWa[2][576 * 4];       //  18432 B
                                                                 // 159744 B

    const int t    = threadIdx.x;
    const int wave = __builtin_amdgcn_readfirstlane(t >> 6);
    const int lane = t & 63;
    const int quad = lane >> 4, m16 = lane & 15;
    const int rw   = wave >> 2;          // row within pair
    const int qb   = (wave & 3) * 16;    // px strip base

    const int blk = blockIdx.x;          // 0..255
    const int xcd = blk & 7;             // L2 image pinning (R2 win)
    const int i5  = blk >> 3;            // 0..31 within XCD
    const int b   = (xcd << 1) | (i5 >> 4);
    const int R4  = (i5 & 15) * 4;       // first of the 4 rows
    const int base = R4 - WLO;           // window first row (may be <0)

    const float* offb = offset + b * (2 * KK * HW);
    const float* mb   = mask + b * (KK * HW);
    const char* xtb   = (const char*)(xt + b * (HW * 64));

    // ---- Prologue loads first (params vmem oldest; staging stays in
    //      flight under the params compute) ----
    float oyv[2][3], oxv[2][3], mkv[2][3];
#pragma unroll
    for (int pr = 0; pr < 2; ++pr)
#pragma unroll
        for (int p = 0; p < 3; ++p) {
            const int it = p * 512 + t;
            if (it < 1152) {
                const int rsel = it >= 576;
                const int j = it - rsel * 576;
                const int tap = j >> 6, q = j & 63;
                const int rowX = R4 + pr * 2 + rsel;
                oyv[pr][p] = offb[(2 * tap) * HW + rowX * 64 + q];
                oxv[pr][p] = offb[(2 * tap + 1) * HW + rowX * 64 + q];
                mkv[pr][p] = mb[tap * HW + rowX * 64 + q];
            } else { oyv[pr][p] = 0.f; oxv[pr][p] = 0.f; mkv[pr][p] = 0.f; }
        }
    asm volatile("" :: "v"(oyv[0][0]), "v"(oxv[0][0]), "v"(mkv[0][0]),
                       "v"(oyv[0][1]), "v"(oxv[0][1]), "v"(mkv[0][1]),
                       "v"(oyv[0][2]), "v"(oxv[0][2]), "v"(mkv[0][2]));
    asm volatile("" :: "v"(oyv[1][0]), "v"(oxv[1][0]), "v"(mkv[1][0]),
                       "v"(oyv[1][1]), "v"(oxv[1][1]), "v"(mkv[1][1]),
                       "v"(oyv[1][2]), "v"(oxv[1][2]), "v"(mkv[1][2]));

    // ---- Stage window: 15 rows x 8 KB, async global->LDS, swizzled source.
    //      LDS dest linear (HW rule: base + lane*16); global source carries
    //      the inverse swizzle: chan-block s' of pixel pxl holds global
    //      chan-block s' ^ (pxl&7). ----
    const int pxl = t >> 3;
    const int swb = ((t & 7) ^ (pxl & 7)) << 4;
#pragma unroll
    for (int s = 0; s < WROWS; ++s) {
        const int srcrow = min(max(base + s, 0), HH - 1);
        const char* src = xtb + srcrow * 8192 + pxl * 128 + swb;
        __builtin_amdgcn_global_load_lds(
            (const __attribute__((address_space(1))) unsigned int*)src,
            (__attribute__((address_space(3))) unsigned int*)
                ((char*)win + s * 8192 + t * 16),
            16, 0, 0);
    }
    __builtin_amdgcn_sched_barrier(0);

    // ---- Param compute for one pair -> PWw/PWa.
    //      PWa: per-corner pre-swizzled window byte offset
    //           enc(w) = (w<<7) | ((w&7)<<4);  esc flag in bit 31 of .x
    auto computePW = [&](int pr) {
#pragma unroll
        for (int p = 0; p < 3; ++p) {
            const int it = p * 512 + t;
            if (it < 1152) {
                const int rsel = it >= 576;
                const int j = it - rsel * 576;
                const int tap = j >> 6, q = j & 63;
                const int rowX = R4 + pr * 2 + rsel;
                const int ky = (tap * 11) >> 5;      // tap/3 for 0..8
                const int kx = tap - ky * 3;
                const float py  = oyv[pr][p] + (float)(rowX - 1 + ky);
                const float pxf = oxv[pr][p] + (float)(q - 1 + kx);
                const float y0f = floorf(py), x0f = floorf(pxf);
                const float wy = py - y0f, wx = pxf - x0f;
                const int y0 = (int)y0f, x0 = (int)x0f;
                const int y1 = y0 + 1,   x1 = x0 + 1;
                const float vy0 = (y0 >= 0 && y0 < HH) ? 1.f : 0.f;
                const float vy1 = (y1 >= 0 && y1 < HH) ? 1.f : 0.f;
                const float vx0 = (x0 >= 0 && x0 < WW) ? 1.f : 0.f;
                const float vx1 = (x1 >= 0 && x1 < WW) ? 1.f : 0.f;
                const float mk = mkv[pr][p];
                const float w00 = (1.f - wy) * (1.f - wx) * vy0 * vx0 * mk;
                const float w01 = (1.f - wy) * wx         * vy0 * vx1 * mk;
                const float w10 = wy * (1.f - wx)         * vy1 * vx0 * mk;
                const float w11 = wy * wx                 * vy1 * vx1 * mk;
                const int cy0 = min(max(y0, 0), HH - 1);
                const int cy1 = min(max(y1, 0), HH - 1);
                const int cx0 = min(max(x0, 0), WW - 1);
                const int cx1 = min(max(x1, 0), WW - 1);
                const int sl0 = cy0 - base, sl1 = cy1 - base;
                const unsigned esc = (sl0 < 0) | (sl1 > (WROWS - 1));
                const int c0 = min(max(sl0, 0), WROWS - 1);
                const int c1 = min(max(sl1, 0), WROWS - 1);
                const int wl00 = c0 * 64 + cx0, wl01 = c0 * 64 + cx1;
                const int wl10 = c1 * 64 + cx0, wl11 = c1 * 64 + cx1;
                const unsigned int s00 = f32_to_f16u(w00);
                const unsigned int s01 = f32_to_f16u(w01);
                const unsigned int s10 = f32_to_f16u(w10);
                const unsigned int s11 = f32_to_f16u(w11);
                int4 P0;
                P0.x = (int)(s00 | (s00 << 16));   // (w,w) half2 pairs
                P0.y = (int)(s01 | (s01 << 16));
                P0.z = (int)(s10 | (s10 << 16));
                P0.w = (int)(s11 | (s11 << 16));
                *(int4*)&PWw[rsel][j * 4] = P0;
                uint4 A;
                A.x = (unsigned)((wl00 << 7) | ((wl00 & 7) << 4)) | (esc << 31);
                A.y = (unsigned)((wl01 << 7) | ((wl01 & 7) << 4));
                A.z = (unsigned)((wl10 << 7) | ((wl10 & 7) << 4));
                A.w = (unsigned)((wl11 << 7) | ((wl11 & 7) << 4));
                *(uint4*)&PWa[rsel][j * 4] = A;
            }
        }
    };

    const char* winc = (const char*)win;

    auto computePair = [&](int pr) {
        f32x4 acc[4];
#pragma unroll
        for (int ot = 0; ot < 4; ++ot)
#pragma unroll
            for (int r = 0; r < 4; ++r) acc[ot][r] = 0.f;

        const int rowX = R4 + pr * 2 + rw;
#pragma unroll
        for (int kc = 0; kc < 3; ++kc) {
            const unsigned short* wkc = wt + kc * (6 * 4 * 512);
#pragma unroll
            for (int ks = 0; ks < 6; ++ks) {
                const int tap = kc * 3 + (ks >> 1);
                const int it  = tap * 64 + qb + m16;
                const uint4 A  = *(const uint4*)&PWa[rw][it * 4];  // bcast x4
                const int4  p0 = *(const int4*)&PWw[rw][it * 4];   // bcast x4
                const unsigned sswz = (unsigned)(((ks & 1) * 4 + quad) << 4);
                uint4 q0 = *(const uint4*)(winc + ((A.x & 0x7FFFFFFFu) ^ sswz));
                uint4 q1 = *(const uint4*)(winc + (A.y ^ sswz));
                uint4 q2 = *(const uint4*)(winc + (A.z ^ sswz));
                uint4 q3 = *(const uint4*)(winc + (A.w ^ sswz));
                if (__builtin_expect(__any((int)(A.x >> 31)), 0)) {  // ~never
                    if (A.x >> 31) {
                        const int q = qb + m16;
                        const int ky = (tap * 11) >> 5;
                        const int kx = tap - ky * 3;
                        const float oy = offb[(2 * tap) * HW + rowX * 64 + q];
                        const float ox = offb[(2 * tap + 1) * HW + rowX * 64 + q];
                        const float py  = oy + (float)(rowX - 1 + ky);
                        const float pxf = ox + (float)(q - 1 + kx);
                        const int y0 = (int)floorf(py), x0 = (int)floorf(pxf);
                        const int cy0 = min(max(y0, 0), HH - 1);
                        const int cy1 = min(max(y0 + 1, 0), HH - 1);
                        const int cx0 = min(max(x0, 0), WW - 1);
                        const int cx1 = min(max(x0 + 1, 0), WW - 1);
                        const int hoff = (ks & 1) * 64 + quad * 16;
                        q0 = *(const uint4*)(xtb + ((cy0 * 64 + cx0) << 7) + hoff);
                        q1 = *(const uint4*)(xtb + ((cy0 * 64 + cx1) << 7) + hoff);
                        q2 = *(const uint4*)(xtb + ((cy1 * 64 + cx0) << 7) + hoff);
                        q3 = *(const uint4*)(xtb + ((cy1 * 64 + cx1) << 7) + hoff);
                    }
                }
                const __half2 c00 = as_h2((unsigned)p0.x);
                const __half2 c01 = as_h2((unsigned)p0.y);
                const __half2 c10 = as_h2((unsigned)p0.z);
                const __half2 c11 = as_h2((unsigned)p0.w);
                uint4 ov;
                {
                    __half2 v = __hmul2(c00, as_h2(q0.x));
                    v = __hfma2(c01, as_h2(q1.x), v);
                    v = __hfma2(c10, as_h2(q2.x), v);
                    v = __hfma2(c11, as_h2(q3.x), v);
                    ov.x = as_u32(v);
                }
                {
                    __half2 v = __hmul2(c00, as_h2(q0.y));
                    v = __hfma2(c01, as_h2(q1.y), v);
                    v = __hfma2(c10, as_h2(q2.y), v);
                    v = __hfma2(c11, as_h2(q3.y), v);
                    ov.y = as_u32(v);
                }
                {
                    __half2 v = __hmul2(c00, as_h2(q0.z));
                    v = __hfma2(c01, as_h2(q1.z), v);
                    v = __hfma2(c10, as_h2(q2.z), v);
                    v = __hfma2(c11, as_h2(q3.z), v);
                    ov.z = as_u32(v);
                }
                {
                    __half2 v = __hmul2(c00, as_h2(q0.w));
                    v = __hfma2(c01, as_h2(q1.w), v);
                    v = __hfma2(c10, as_h2(q2.w), v);
                    v = __hfma2(c11, as_h2(q3.w), v);
                    ov.w = as_u32(v);
                }
                f16x8 bfrag;
                __builtin_memcpy(&bfrag, &ov, 16);
#pragma unroll
                for (int ot = 0; ot < 4; ++ot) {
                    const f16x8 afrag =
                        *(const f16x8*)(wkc + (ks * 4 + ot) * 512 + lane * 8);
                    acc[ot] = __builtin_amdgcn_mfma_f32_16x16x32_f16(
                        afrag, bfrag, acc[ot], 0, 0, 0);
                }
            }
        }

        float* ob = out + b * (COUT * HW) + rowX * 64 + qb + m16;
#pragma unroll
        for (int ot = 0; ot < 4; ++ot)
#pragma unroll
            for (int r = 0; r < 4; ++r) {
                const int o = ot * 16 + quad * 4 + r;
                ob[o * HW] = acc[ot][r] + bias[o];
            }
    };

    computePW(0);
    __syncthreads();   // staging (vmcnt drained) + pair-0 params visible
    computePair(0);
    __syncthreads();   // all waves done reading pair-0 PW
    computePW(1);
    __syncthreads();   // pair-1 params visible
    computePair(1);
}

extern "C" void kernel_launch(void* const* d_in, const int* in_sizes, int n_in,
                              void* d_out, int out_size, void* d_ws,
                              size_t ws_size, hipStream_t stream) {
    const float* x    = (const float*)d_in[0];
    const float* off  = (const float*)d_in[1];
    const float* mask = (const float*)d_in[2];
    const float* w    = (const float*)d_in[3];
    const float* bias = (const float*)d_in[4];
    float* out = (float*)d_out;

    unsigned short* xt = (unsigned short*)d_ws;                     // 8388608 B
    unsigned short* wt = (unsigned short*)((char*)d_ws + 8388608);  // 73728 B

    prep_kernel<<<1024 + 144, 256, 0, stream>>>(x, w, xt, wt);
    dcn_main_kernel<<<256, 512, 0, stream>>>(off, mask, xt, wt, bias, out);
}